// Round 9
// baseline (660.364 us; speedup 1.0000x reference)
//
#include <hip/hip_runtime.h>

// SOM BMU one-hot via split-bf16 MFMA GEMM. R9 structure:
//   som_prep : w -> w3 (8-slot swizzled B-frags [wh x4 | wl x4], 512 KB) + wsq
//   som_main : 256-thr blocks = 4 waves x 32 samples sharing one B stream
//              (identical b-load addresses across waves -> 3/4 L1 hits,
//              aggregate L2 traffic 1.6 GB -> 0.4 GB). No LDS, no barriers.
//   som_pass2: fp64 re-solve, one 1024-thread block per flagged row
//
// R8 post-mortem: all kernels < 257 us poison-fill (untouchable floor);
// controllable budget ~390 us. Main's waste: 3125 waves x private 512 KB
// L2 stream. R9 shares it 4-ways via co-blocked waves hitting L1.

typedef __attribute__((ext_vector_type(8))) short bf16x8;   // 8 bf16 = 4 VGPR
typedef __attribute__((ext_vector_type(4))) float f32x4;

#define SOM_K 1024
#define SOM_D 128
#define MARGIN 0.02f
#define FLAG_CAP 8192

// d_ws layout (bytes):
#define WS_WSQ   64        // 1024 f32  (4 KB)
#define WS_W3    8192      // 64 tiles x 8 slots x 64 lanes x 8 bf16 (512 KB)
#define WS_FLAGS 532480    // 8192 int  (32 KB) -> ends ~565 KB

static __device__ __forceinline__ unsigned short f2bf(float f) {
    unsigned u = __float_as_uint(f);
    return (unsigned short)((u + 0x7FFFu + ((u >> 16) & 1u)) >> 16);  // RNE
}
static __device__ __forceinline__ float bf2f(unsigned short h) {
    return __uint_as_float(((unsigned)h) << 16);
}

// ---- prep: w -> w3 (swizzled split-bf16, 8 slots) + exact wsq -------------
// w3 element for (proto n, inner kk in [0,256)): s=kk>>5 (slot), q=(kk>>3)&3,
// j=kk&7, nt=n>>4, c=n&15:  flat = ((nt*8+s)*64 + q*16 + c)*8 + j.
__global__ __launch_bounds__(256) void som_prep(
    const float* __restrict__ w, unsigned short* __restrict__ w3,
    float* __restrict__ wsq)
{
    __shared__ float ws_[16][SOM_D];     // 8 KB staging for 16 protos
    const int nt = blockIdx.x;           // tile 0..63
    const int tid = threadIdx.x;

    const float* src = w + (size_t)nt * 16 * SOM_D;
    #pragma unroll
    for (int r = 0; r < 8; ++r) {
        const int e = r * 256 + tid;
        ws_[e >> 7][e & 127] = src[e];
    }
    __syncthreads();

    unsigned short* dst = w3 + (size_t)nt * 4096;
    #pragma unroll
    for (int r = 0; r < 2; ++r) {
        const int G = r * 256 + tid;     // 0..511
        const int s = G >> 6;            // slot 0..7
        const int l = G & 63;            // lane
        const int c = l & 15, q = l >> 4;
        bf16x8 v;
        #pragma unroll
        for (int j = 0; j < 8; ++j) {
            const int kk = 32 * s + 8 * q + j;       // 0..255
            const int d = kk & 127;
            const float f = ws_[c][d];
            const unsigned short h = f2bf(f);
            v[j] = (short)((kk & 128) ? f2bf(f - bf2f(h)) : h);  // wl : wh
        }
        *(bf16x8*)(dst + G * 8) = v;
    }

    if (tid < 16) {
        double s = 0.0;
        #pragma unroll 16
        for (int d = 0; d < SOM_D; ++d) {
            double v = (double)ws_[tid][d];
            s += v * v;
        }
        wsq[nt * 16 + tid] = (float)s;
    }
}

// ---- main: 4 waves/block share B stream; MFMA + argmin + one-hot ----------
__global__ __launch_bounds__(256, 2) void som_main(
    const float* __restrict__ x,
    const unsigned short* __restrict__ w3,
    const float* __restrict__ wsq,
    float* __restrict__ out,
    int* __restrict__ flag_count,
    int* __restrict__ flag_list,
    int n_samples)
{
    const int lane = threadIdx.x & 63;
    const int wv   = threadIdx.x >> 6;       // wave 0..3
    const int c = lane & 15;
    const int q = lane >> 4;
    const int R0 = blockIdx.x * 128 + wv * 32;   // 782 blocks x 128 rows

    // a-frags: A[m=lane&15][k=8q+j], two 16-row groups, hi+lo (64 VGPR).
    bf16x8 ah[2][4], al[2][4];
    #pragma unroll
    for (int g = 0; g < 2; ++g) {
        int row = R0 + 16 * g + c;
        if (row >= n_samples) row = n_samples - 1;   // clamp (results unused)
        const float* xp = x + (size_t)row * SOM_D + 8 * q;
        #pragma unroll
        for (int s = 0; s < 4; ++s) {
            float4 v0 = *(const float4*)(xp + 32 * s);
            float4 v1 = *(const float4*)(xp + 32 * s + 4);
            float xv[8] = {v0.x, v0.y, v0.z, v0.w, v1.x, v1.y, v1.z, v1.w};
            bf16x8 hh, ll;
            #pragma unroll
            for (int j = 0; j < 8; ++j) {
                unsigned short h = f2bf(xv[j]);
                hh[j] = (short)h;
                ll[j] = (short)f2bf(xv[j] - bf2f(h));
            }
            ah[g][s] = hh; al[g][s] = ll;
        }
    }

    float best[2][4], sec[2][4];
    int bk[2][4];
    #pragma unroll
    for (int g = 0; g < 2; ++g)
        #pragma unroll
        for (int r = 0; r < 4; ++r) { best[g][r] = 1e30f; sec[g][r] = 1e30f; bk[g][r] = 0; }

    // b-frag base: lane*16B, slot stride 1 KB, tile stride 8 KB.
    // All 4 waves read IDENTICAL addresses -> L1-served after first wave.
    const unsigned short* wbase = w3 + lane * 8;

    #pragma unroll 1
    for (int nt = 0; nt < 64; ++nt) {
        const int n0 = nt * 16;
        const unsigned short* wp = wbase + (size_t)nt * 4096;
        bf16x8 b[8];
        #pragma unroll
        for (int s = 0; s < 8; ++s) b[s] = *(const bf16x8*)(wp + 512 * s);
        const float wq = wsq[n0 + c];

        f32x4 a0 = {0.f, 0.f, 0.f, 0.f}, a1 = {0.f, 0.f, 0.f, 0.f};
        #pragma unroll
        for (int s = 0; s < 4; ++s) {   // xh * wh
            a0 = __builtin_amdgcn_mfma_f32_16x16x32_bf16(ah[0][s], b[s], a0, 0, 0, 0);
            a1 = __builtin_amdgcn_mfma_f32_16x16x32_bf16(ah[1][s], b[s], a1, 0, 0, 0);
        }
        #pragma unroll
        for (int s = 0; s < 4; ++s) {   // xh * wl
            a0 = __builtin_amdgcn_mfma_f32_16x16x32_bf16(ah[0][s], b[4 + s], a0, 0, 0, 0);
            a1 = __builtin_amdgcn_mfma_f32_16x16x32_bf16(ah[1][s], b[4 + s], a1, 0, 0, 0);
        }
        #pragma unroll
        for (int s = 0; s < 4; ++s) {   // xl * wh -- reuses b[0..3]
            a0 = __builtin_amdgcn_mfma_f32_16x16x32_bf16(al[0][s], b[s], a0, 0, 0, 0);
            a1 = __builtin_amdgcn_mfma_f32_16x16x32_bf16(al[1][s], b[s], a1, 0, 0, 0);
        }

        #pragma unroll
        for (int r = 0; r < 4; ++r) {
            float s0 = wq - 2.f * a0[r];
            if (s0 < best[0][r]) { sec[0][r] = best[0][r]; best[0][r] = s0; bk[0][r] = n0 + c; }
            else if (s0 < sec[0][r]) sec[0][r] = s0;
            float s1 = wq - 2.f * a1[r];
            if (s1 < best[1][r]) { sec[1][r] = best[1][r]; best[1][r] = s1; bk[1][r] = n0 + c; }
            else if (s1 < sec[1][r]) sec[1][r] = s1;
        }
    }

    // reduce across the 16 c-lanes of each quad-group (result in all lanes)
    #pragma unroll
    for (int g = 0; g < 2; ++g) {
        #pragma unroll
        for (int r = 0; r < 4; ++r) {
            float b0v = best[g][r], s0v = sec[g][r];
            int k0 = bk[g][r];
            #pragma unroll
            for (int m = 1; m < 16; m <<= 1) {
                float ob = __shfl_xor(b0v, m);
                float os = __shfl_xor(s0v, m);
                int   ok = __shfl_xor(k0, m);
                if (ob < b0v || (ob == b0v && ok < k0)) {
                    s0v = fminf(b0v, os); b0v = ob; k0 = ok;
                } else {
                    s0v = fminf(s0v, ob);
                }
            }
            best[g][r] = b0v; sec[g][r] = s0v; bk[g][r] = k0;
        }
    }

    if (c == 0) {   // lanes 0,16,32,48 hold rows g*16 + 4q + r
        #pragma unroll
        for (int g = 0; g < 2; ++g) {
            #pragma unroll
            for (int r = 0; r < 4; ++r) {
                const int row = R0 + g * 16 + 4 * q + r;
                if (row < n_samples && (sec[g][r] - best[g][r]) < MARGIN) {
                    int i = atomicAdd(flag_count, 1);
                    if (i < FLAG_CAP) flag_list[i] = row;
                }
            }
        }
    }

    // fused one-hot write: row rr's bmu lives in quad (rr>>2)&3, reg rr&3
    #pragma unroll 1
    for (int rr = 0; rr < 32; ++rr) {
        const int row = R0 + rr;
        if (row >= n_samples) break;     // tail guard (rows are ascending)
        const int g = rr >> 4, qq = (rr >> 2) & 3, r = rr & 3;
        const int b = __shfl(bk[g][r], qq << 4);
        f32x4* op = (f32x4*)(out + (size_t)row * SOM_K);
        #pragma unroll
        for (int j = 0; j < 4; ++j) {
            const int e = j * 64 + lane;
            f32x4 v = {0.f, 0.f, 0.f, 0.f};
            if ((b >> 2) == e) v[b & 3] = 1.0f;
            __builtin_nontemporal_store(v, op + e);
        }
    }
}

// ---- pass2: fp64 re-solve, one 1024-thread block per flagged row ----------
__global__ __launch_bounds__(1024) void som_pass2(
    const float* __restrict__ x,
    const float* __restrict__ w,
    float* __restrict__ out,
    const int* __restrict__ flag_count,
    const int* __restrict__ flag_list)
{
    __shared__ float xs[SOM_D];
    __shared__ double rbest[16];
    __shared__ int    rk[16];

    const int tid  = threadIdx.x;          // == proto k
    const int lane = tid & 63;
    const int wv   = tid >> 6;             // wave 0..15
    int cnt = *flag_count;
    if (cnt > FLAG_CAP) cnt = FLAG_CAP;

    for (int i = blockIdx.x; i < cnt; i += gridDim.x) {
        const int row = flag_list[i];
        __syncthreads();                   // guard xs/red reuse
        if (tid < SOM_D) xs[tid] = x[(size_t)row * SOM_D + tid];
        __syncthreads();

        // exact fp64 score for proto k = tid (contiguous per-lane w stream)
        const float* wk = w + (size_t)tid * SOM_D;
        double s0 = 0.0, s1 = 0.0;
        #pragma unroll
        for (int d = 0; d < SOM_D; d += 4) {
            float4 wv4 = *(const float4*)(wk + d);
            double w0 = (double)wv4.x, w1 = (double)wv4.y;
            double w2 = (double)wv4.z, w3 = (double)wv4.w;
            s0 += w0 * (w0 - 2.0 * (double)xs[d])     + w2 * (w2 - 2.0 * (double)xs[d + 2]);
            s1 += w1 * (w1 - 2.0 * (double)xs[d + 1]) + w3 * (w3 - 2.0 * (double)xs[d + 3]);
        }
        double sc = s0 + s1;
        int bk = tid;

        // wave argmin (tie -> smaller k)
        #pragma unroll
        for (int off = 32; off > 0; off >>= 1) {
            double os = __shfl_down(sc, off);
            int    ok = __shfl_down(bk, off);
            if (os < sc || (os == sc && ok < bk)) { sc = os; bk = ok; }
        }
        if (lane == 0) { rbest[wv] = sc; rk[wv] = bk; }
        __syncthreads();

        if (tid == 0) {
            double b = rbest[0]; int k0 = rk[0];
            #pragma unroll
            for (int v = 1; v < 16; ++v) {
                if (rbest[v] < b || (rbest[v] == b && rk[v] < k0)) { b = rbest[v]; k0 = rk[v]; }
            }
            rk[0] = k0;
        }
        __syncthreads();
        const int bmu = rk[0];

        out[(size_t)row * SOM_K + tid] = (tid == bmu) ? 1.0f : 0.0f;
    }
}

extern "C" void kernel_launch(void* const* d_in, const int* in_sizes, int n_in,
                              void* d_out, int out_size, void* d_ws, size_t ws_size,
                              hipStream_t stream) {
    const float* x = (const float*)d_in[0];
    const float* w = (const float*)d_in[1];
    float* out = (float*)d_out;

    const int n_samples = in_sizes[0] / SOM_D;  // 100000

    char* ws = (char*)d_ws;
    int*            flag_count = (int*)ws;
    float*          wsq        = (float*)(ws + WS_WSQ);
    unsigned short* w3         = (unsigned short*)(ws + WS_W3);
    int*            flag_list  = (int*)(ws + WS_FLAGS);

    (void)hipMemsetAsync(d_ws, 0, 64, stream);   // flag counter

    som_prep<<<64, 256, 0, stream>>>(w, w3, wsq);
    const int grid = (n_samples + 127) / 128;    // 782
    som_main<<<grid, 256, 0, stream>>>(x, w3, wsq, out, flag_count, flag_list,
                                       n_samples);
    som_pass2<<<256, 1024, 0, stream>>>(x, w, out, flag_count, flag_list);
}